// Round 1
// baseline (385.451 us; speedup 1.0000x reference)
//
#include <hip/hip_runtime.h>
#include <math.h>

#define TT 8192
#define HH 5120
#define EE 160
#define NGRP 8
#define GSZ 20
#define TOPKG 3
#define TOPK 6
#define RSCALE 16.0f

#define BM 32
#define BK 64
#define PK (BK + 1)    // 65: padded K stride, conflict-free scalar reads
#define PS (EE + 1)    // 161: padded score stride

__global__ __launch_bounds__(256) void moe_gate_fused(
    const float* __restrict__ Ag,   // [TT][HH] hidden_states
    const float* __restrict__ Bg,   // [EE][HH] gating kernel
    float* __restrict__ out)        // [TT][TOPK]
{
    // LDS: As [BM][PK] + Bs [EE][PK]; Sc [BM][PS] aliases Bs (used after GEMM)
    __shared__ float smem[BM * PK + EE * PK];   // 12480 floats = 49920 B
    float* As = smem;
    float* Bs = smem + BM * PK;
    float* Sc = smem + BM * PK;     // 32*161 = 5152 <= 160*65 = 10400 OK

    const int t   = threadIdx.x;
    const int bm0 = blockIdx.x * BM;

    // compute mapping: thread owns 4 tokens x 5 experts
    const int tm = t & 7;          // token quad: local tokens 4*tm..4*tm+3
    const int te = t >> 3;         // expert slot: experts 5*te..5*te+4

    float acc[4][5];
    #pragma unroll
    for (int i = 0; i < 4; i++)
        #pragma unroll
        for (int j = 0; j < 5; j++) acc[i][j] = 0.f;

    // load mapping
    const int lr = t >> 4;          // 0..15
    const int lc = (t & 15) << 2;   // 0,4,...,60

    const int aBase = (4 * tm) * PK;
    const int bBase = (5 * te) * PK;

    for (int k0 = 0; k0 < HH; k0 += BK) {
        __syncthreads();
        // ---- A tile: 32 rows x 64 cols, rows lr and lr+16
        {
            float4 v0 = *reinterpret_cast<const float4*>(Ag + (size_t)(bm0 + lr) * HH + k0 + lc);
            float4 v1 = *reinterpret_cast<const float4*>(Ag + (size_t)(bm0 + lr + 16) * HH + k0 + lc);
            As[lr * PK + lc + 0] = v0.x; As[lr * PK + lc + 1] = v0.y;
            As[lr * PK + lc + 2] = v0.z; As[lr * PK + lc + 3] = v0.w;
            As[(lr + 16) * PK + lc + 0] = v1.x; As[(lr + 16) * PK + lc + 1] = v1.y;
            As[(lr + 16) * PK + lc + 2] = v1.z; As[(lr + 16) * PK + lc + 3] = v1.w;
        }
        // ---- B tile: 160 rows x 64 cols, experts lr + 16*i
        #pragma unroll
        for (int i = 0; i < 10; i++) {
            int e = lr + 16 * i;
            float4 v = *reinterpret_cast<const float4*>(Bg + (size_t)e * HH + k0 + lc);
            Bs[e * PK + lc + 0] = v.x; Bs[e * PK + lc + 1] = v.y;
            Bs[e * PK + lc + 2] = v.z; Bs[e * PK + lc + 3] = v.w;
        }
        __syncthreads();

        #pragma unroll 4
        for (int k = 0; k < BK; k++) {
            float a0 = As[aBase + 0 * PK + k];
            float a1 = As[aBase + 1 * PK + k];
            float a2 = As[aBase + 2 * PK + k];
            float a3 = As[aBase + 3 * PK + k];
            float b0 = Bs[bBase + 0 * PK + k];
            float b1 = Bs[bBase + 1 * PK + k];
            float b2 = Bs[bBase + 2 * PK + k];
            float b3 = Bs[bBase + 3 * PK + k];
            float b4 = Bs[bBase + 4 * PK + k];
            acc[0][0] = fmaf(a0, b0, acc[0][0]); acc[0][1] = fmaf(a0, b1, acc[0][1]);
            acc[0][2] = fmaf(a0, b2, acc[0][2]); acc[0][3] = fmaf(a0, b3, acc[0][3]);
            acc[0][4] = fmaf(a0, b4, acc[0][4]);
            acc[1][0] = fmaf(a1, b0, acc[1][0]); acc[1][1] = fmaf(a1, b1, acc[1][1]);
            acc[1][2] = fmaf(a1, b2, acc[1][2]); acc[1][3] = fmaf(a1, b3, acc[1][3]);
            acc[1][4] = fmaf(a1, b4, acc[1][4]);
            acc[2][0] = fmaf(a2, b0, acc[2][0]); acc[2][1] = fmaf(a2, b1, acc[2][1]);
            acc[2][2] = fmaf(a2, b2, acc[2][2]); acc[2][3] = fmaf(a2, b3, acc[2][3]);
            acc[2][4] = fmaf(a2, b4, acc[2][4]);
            acc[3][0] = fmaf(a3, b0, acc[3][0]); acc[3][1] = fmaf(a3, b1, acc[3][1]);
            acc[3][2] = fmaf(a3, b2, acc[3][2]); acc[3][3] = fmaf(a3, b3, acc[3][3]);
            acc[3][4] = fmaf(a3, b4, acc[3][4]);
        }
    }

    // ---- stash scores (logits) to LDS, transposing ownership to per-token rows
    __syncthreads();   // everyone done reading Bs before overwrite (Sc aliases Bs)
    #pragma unroll
    for (int i = 0; i < 4; i++)
        #pragma unroll
        for (int j = 0; j < 5; j++)
            Sc[(4 * tm + i) * PS + (5 * te + j)] = acc[i][j];
    __syncthreads();

    // ---- routing: one wave per token, 8 tokens per wave
    const int w = t >> 6;
    const int l = t & 63;

    for (int it = 0; it < 8; ++it) {
        const int r = w * 8 + it;
        float s0 = Sc[r * PS + l];
        float s1 = Sc[r * PS + 64 + l];
        float s2 = (l < 32) ? Sc[r * PS + 128 + l] : -INFINITY;

        // softmax over 160
        float m = fmaxf(s0, fmaxf(s1, s2));
        #pragma unroll
        for (int off = 32; off >= 1; off >>= 1) m = fmaxf(m, __shfl_xor(m, off, 64));
        float p0 = expf(s0 - m);
        float p1 = expf(s1 - m);
        float p2 = (l < 32) ? expf(s2 - m) : 0.f;
        float sum = p0 + p1 + p2;
        #pragma unroll
        for (int off = 32; off >= 1; off >>= 1) sum += __shfl_xor(sum, off, 64);
        float inv = 1.0f / sum;
        p0 *= inv; p1 *= inv; p2 *= inv;

        // group ids per slot
        const int g0 = l / GSZ;            // 0..3
        const int g1 = (l + 64) / GSZ;     // 3..6
        const int g2 = (l + 128) / GSZ;    // 6..7 (valid l<32)

        // group maxes (uniform result on all lanes)
        float gmax[NGRP];
        #pragma unroll
        for (int g = 0; g < NGRP; g++) {
            float v = -1.f;
            if (g0 == g) v = p0;
            if (g1 == g) v = fmaxf(v, p1);
            if (l < 32 && g2 == g) v = fmaxf(v, p2);
            #pragma unroll
            for (int off = 32; off >= 1; off >>= 1) v = fmaxf(v, __shfl_xor(v, off, 64));
            gmax[g] = v;
        }

        // top-3 groups, ties -> lowest index (strict >)
        int selmask = 0;
        #pragma unroll
        for (int s = 0; s < TOPKG; s++) {
            float best = -2.f; int bg = 0;
            #pragma unroll
            for (int g = 0; g < NGRP; g++) {
                if (!((selmask >> g) & 1) && gmax[g] > best) { best = gmax[g]; bg = g; }
            }
            selmask |= 1 << bg;
        }

        // masked scores (0 for unselected groups, matches reference); -1 = invalid slot
        float m0 = ((selmask >> g0) & 1) ? p0 : 0.f;
        float m1 = ((selmask >> g1) & 1) ? p1 : 0.f;
        float m2 = (l < 32) ? (((selmask >> g2) & 1) ? p2 : 0.f) : -1.f;

        // iterative top-6 (descending, as jax.lax.top_k values)
        #pragma unroll
        for (int s = 0; s < TOPK; s++) {
            float v = fmaxf(m0, fmaxf(m1, m2));
            #pragma unroll
            for (int off = 32; off >= 1; off >>= 1) v = fmaxf(v, __shfl_xor(v, off, 64));
            int idx = 0x7fffffff;
            if (m0 == v) idx = l;
            if (m1 == v) idx = min(idx, l + 64);
            if (l < 32 && m2 == v) idx = min(idx, l + 128);
            #pragma unroll
            for (int off = 32; off >= 1; off >>= 1) idx = min(idx, __shfl_xor(idx, off, 64));
            // clear the winner (exactly one slot holds expert idx)
            if (idx == l)            m0 = -1.f;
            else if (idx == l + 64)  m1 = -1.f;
            else if (l < 32 && idx == l + 128) m2 = -1.f;
            if (l == 0) out[(size_t)(bm0 + r) * TOPK + s] = v * RSCALE;
        }
    }
}

extern "C" void kernel_launch(void* const* d_in, const int* in_sizes, int n_in,
                              void* d_out, int out_size, void* d_ws, size_t ws_size,
                              hipStream_t stream) {
    const float* hs = (const float*)d_in[0];   // [8192][5120] fp32
    const float* kn = (const float*)d_in[1];   // [160][5120] fp32
    float* o = (float*)d_out;                  // [8192][6] fp32
    dim3 grid(TT / BM);
    dim3 block(256);
    hipLaunchKernelGGL(moe_gate_fused, grid, block, 0, stream, hs, kn, o);
}

// Round 3
// 148.761 us; speedup vs baseline: 2.5911x; 2.5911x over previous
//
#include <hip/hip_runtime.h>
#include <math.h>

#define TT 8192
#define HH 5120
#define EE 160
#define NGRP 8
#define GSZ 20
#define TOPKG 3
#define TOPK 6
#define RSCALE 16.0f

typedef __attribute__((ext_vector_type(8))) short bf16x8;
typedef __attribute__((ext_vector_type(4))) float f32x4;

#define BW_ELEMS ((size_t)160 * 10 * 64 * 8)   // 819200 ushorts per B copy

__device__ __forceinline__ ushort f2bf(float f) {
    uint32_t u = __float_as_uint(f);
    u += 0x7fff + ((u >> 16) & 1);   // RNE
    return (ushort)(u >> 16);
}
__device__ __forceinline__ float bf2f(ushort h) {
    return __uint_as_float(((uint32_t)h) << 16);
}

// ---------------- Kernel 1: B [160][5120] fp32 -> bf16 hi+lo fragment-linear ----
// layout per copy: [kt 0..159][et 0..9][lane 0..63][8 bf16]; lane&15 = expert,
// lane>>4 = k-octet -> mfma_f32_16x16x32_bf16 B-operand frag. Lo copy at +BW_ELEMS.
__global__ __launch_bounds__(256) void prep_b(const float* __restrict__ B,
                                              ushort* __restrict__ Bw) {
    int gid = blockIdx.x * 256 + threadIdx.x;        // < 102400
    int lane = gid & 63;
    int et   = (gid >> 6) % 10;
    int kt   = gid / 640;
    int e = et * 16 + (lane & 15);
    int c = kt * 32 + (lane >> 4) * 8;
    const float* src = B + (size_t)e * HH + c;
    uint4 vh, vl;
    uint32_t hw[8], lw[8];
    #pragma unroll
    for (int j = 0; j < 8; j++) {
        float f = src[j];
        ushort h = f2bf(f);
        float r = f - bf2f(h);
        hw[j] = h;
        lw[j] = f2bf(r);
    }
    vh.x = hw[0] | (hw[1] << 16); vh.y = hw[2] | (hw[3] << 16);
    vh.z = hw[4] | (hw[5] << 16); vh.w = hw[6] | (hw[7] << 16);
    vl.x = lw[0] | (lw[1] << 16); vl.y = lw[2] | (lw[3] << 16);
    vl.z = lw[4] | (lw[5] << 16); vl.w = lw[6] | (lw[7] << 16);
    *reinterpret_cast<uint4*>(Bw + (size_t)gid * 8) = vh;
    *reinterpret_cast<uint4*>(Bw + BW_ELEMS + (size_t)gid * 8) = vl;
}

// ---------------- Kernel 2: fused MFMA gemm + softmax + group-topk routing ------
#define BM 32
#define BK 256
#define NT (HH / BK)     // 20
#define PS (EE + 1)      // 161

__global__ __launch_bounds__(512) void moe_mfma(const float* __restrict__ A,
                                                const ushort* __restrict__ Bw,
                                                float* __restrict__ out) {
    // LDS: AH 16KB | AL 16KB | Sc 32x161 f32 (20608B)
    __shared__ char lds[32768 + BM * PS * 4];
    char* AHp = lds;
    char* ALp = lds + 16384;
    float* Sc = (float*)(lds + 32768);

    const int tid = threadIdx.x;
    const int w = tid >> 6, l = tid & 63;
    const int bm0 = blockIdx.x * BM;

    for (int i = tid; i < BM * PS; i += 512) Sc[i] = 0.f;

    // ---- A staging map: thread -> 16 consecutive fp32 of one row
    const int sr   = tid >> 4;            // 0..31 (token row)
    const int scol = (tid & 15) << 4;     // 0..240
    const int sw   = scol >> 5;           // owner wave (K32 slice) 0..7
    const int sg2  = (scol & 31) >> 3;    // 0 or 2 (k-octet group)
    const int r4   = sr & 15;
    const int smt  = sr >> 4;
    const int wb   = (sw * 2 + smt) * 1024;
    const int ws0  = wb + ((sg2 * 16 + r4) ^ sw) * 16;        // XOR swizzle
    const int ws1  = wb + (((sg2 + 1) * 16 + r4) ^ sw) * 16;

    const float* ap = A + (size_t)(bm0 + sr) * HH + scol;

    // ---- A-frag read offsets (lane-linear 16B, same XOR on read side)
    const int rslot = (l ^ (w & 7)) * 16;
    const int ra0 = (w * 2 + 0) * 1024 + rslot;
    const int ra1 = (w * 2 + 1) * 1024 + rslot;

    f32x4 acc[2][10];
    #pragma unroll
    for (int mt = 0; mt < 2; mt++)
        #pragma unroll
        for (int et = 0; et < 10; et++) acc[mt][et] = (f32x4){0.f, 0.f, 0.f, 0.f};

    float4 ga, gb, gc, gd;
    { const float4* p = (const float4*)ap; ga = p[0]; gb = p[1]; gc = p[2]; gd = p[3]; }

    #pragma unroll 1
    for (int t = 0; t < NT; ++t) {
        float4 na = ga, nb = gb, nc = gc, nd = gd;
        if (t + 1 < NT) {          // prefetch next A tile
            const float4* p = (const float4*)(ap + (t + 1) * BK);
            na = p[0]; nb = p[1]; nc = p[2]; nd = p[3];
        }
        // split current 16 fp32 -> bf16 hi/lo
        float fv[16] = {ga.x, ga.y, ga.z, ga.w, gb.x, gb.y, gb.z, gb.w,
                        gc.x, gc.y, gc.z, gc.w, gd.x, gd.y, gd.z, gd.w};
        uint32_t hp[8], lp[8];
        #pragma unroll
        for (int j = 0; j < 8; j++) {
            ushort h0 = f2bf(fv[2*j]), h1 = f2bf(fv[2*j+1]);
            float  l0 = fv[2*j]   - bf2f(h0);
            float  l1 = fv[2*j+1] - bf2f(h1);
            hp[j] = (uint32_t)h0 | ((uint32_t)h1 << 16);
            lp[j] = (uint32_t)f2bf(l0) | ((uint32_t)f2bf(l1) << 16);
        }
        __syncthreads();   // all waves done reading previous tile
        *(uint4*)(AHp + ws0) = make_uint4(hp[0], hp[1], hp[2], hp[3]);
        *(uint4*)(AHp + ws1) = make_uint4(hp[4], hp[5], hp[6], hp[7]);
        *(uint4*)(ALp + ws0) = make_uint4(lp[0], lp[1], lp[2], lp[3]);
        *(uint4*)(ALp + ws1) = make_uint4(lp[4], lp[5], lp[6], lp[7]);
        __syncthreads();   // tile ready

        bf16x8 ah0 = *(bf16x8*)(AHp + ra0);
        bf16x8 ah1 = *(bf16x8*)(AHp + ra1);
        bf16x8 al0 = *(bf16x8*)(ALp + ra0);
        bf16x8 al1 = *(bf16x8*)(ALp + ra1);
        const ushort* bt = Bw + ((size_t)((t * 8 + w) * 10) * 64 + l) * 8;
        #pragma unroll
        for (int et = 0; et < 10; et++) {
            bf16x8 bh = *(const bf16x8*)(bt + et * 512);             // B hi
            bf16x8 bl = *(const bf16x8*)(bt + BW_ELEMS + et * 512);  // B lo
            acc[0][et] = __builtin_amdgcn_mfma_f32_16x16x32_bf16(ah0, bh, acc[0][et], 0, 0, 0);
            acc[1][et] = __builtin_amdgcn_mfma_f32_16x16x32_bf16(ah1, bh, acc[1][et], 0, 0, 0);
            acc[0][et] = __builtin_amdgcn_mfma_f32_16x16x32_bf16(al0, bh, acc[0][et], 0, 0, 0);
            acc[1][et] = __builtin_amdgcn_mfma_f32_16x16x32_bf16(al1, bh, acc[1][et], 0, 0, 0);
            acc[0][et] = __builtin_amdgcn_mfma_f32_16x16x32_bf16(ah0, bl, acc[0][et], 0, 0, 0);
            acc[1][et] = __builtin_amdgcn_mfma_f32_16x16x32_bf16(ah1, bl, acc[1][et], 0, 0, 0);
        }
        ga = na; gb = nb; gc = nc; gd = nd;
    }

    // ---- cross-wave K-reduction into Sc (LDS f32 atomics; static acc indexing)
    const int rrow = (l >> 4) * 4;
    const int rcol = l & 15;
    #pragma unroll
    for (int mt = 0; mt < 2; mt++)
        #pragma unroll
        for (int et = 0; et < 10; et++)
            #pragma unroll
            for (int j = 0; j < 4; j++)
                atomicAdd(&Sc[(mt * 16 + rrow + j) * PS + et * 16 + rcol], acc[mt][et][j]);
    __syncthreads();

    // ---- routing: one wave per token, 4 tokens per wave (validated in R0)
    for (int it = 0; it < 4; ++it) {
        const int r = w * 4 + it;
        float s0 = Sc[r * PS + l];
        float s1 = Sc[r * PS + 64 + l];
        float s2 = (l < 32) ? Sc[r * PS + 128 + l] : -INFINITY;

        float m = fmaxf(s0, fmaxf(s1, s2));
        #pragma unroll
        for (int off = 32; off >= 1; off >>= 1) m = fmaxf(m, __shfl_xor(m, off, 64));
        float p0 = expf(s0 - m);
        float p1 = expf(s1 - m);
        float p2 = (l < 32) ? expf(s2 - m) : 0.f;
        float sum = p0 + p1 + p2;
        #pragma unroll
        for (int off = 32; off >= 1; off >>= 1) sum += __shfl_xor(sum, off, 64);
        float inv = 1.0f / sum;
        p0 *= inv; p1 *= inv; p2 *= inv;

        const int g0 = l / GSZ;
        const int g1 = (l + 64) / GSZ;
        const int g2 = (l + 128) / GSZ;

        float gmax[NGRP];
        #pragma unroll
        for (int g = 0; g < NGRP; g++) {
            float v = -1.f;
            if (g0 == g) v = p0;
            if (g1 == g) v = fmaxf(v, p1);
            if (l < 32 && g2 == g) v = fmaxf(v, p2);
            #pragma unroll
            for (int off = 32; off >= 1; off >>= 1) v = fmaxf(v, __shfl_xor(v, off, 64));
            gmax[g] = v;
        }

        int selmask = 0;
        #pragma unroll
        for (int s = 0; s < TOPKG; s++) {
            float best = -2.f; int bg = 0;
            #pragma unroll
            for (int g = 0; g < NGRP; g++)
                if (!((selmask >> g) & 1) && gmax[g] > best) { best = gmax[g]; bg = g; }
            selmask |= 1 << bg;
        }

        float m0 = ((selmask >> g0) & 1) ? p0 : 0.f;
        float m1 = ((selmask >> g1) & 1) ? p1 : 0.f;
        float m2 = (l < 32) ? (((selmask >> g2) & 1) ? p2 : 0.f) : -1.f;

        #pragma unroll
        for (int s = 0; s < TOPK; s++) {
            float v = fmaxf(m0, fmaxf(m1, m2));
            #pragma unroll
            for (int off = 32; off >= 1; off >>= 1) v = fmaxf(v, __shfl_xor(v, off, 64));
            int idx = 0x7fffffff;
            if (m0 == v) idx = l;
            if (m1 == v) idx = min(idx, l + 64);
            if (l < 32 && m2 == v) idx = min(idx, l + 128);
            #pragma unroll
            for (int off = 32; off >= 1; off >>= 1) idx = min(idx, __shfl_xor(idx, off, 64));
            if (idx == l)            m0 = -1.f;
            else if (idx == l + 64)  m1 = -1.f;
            else if (l < 32 && idx == l + 128) m2 = -1.f;
            if (l == 0) out[(size_t)(bm0 + r) * TOPK + s] = v * RSCALE;
        }
    }
}

// ---------------- Fallback (R0 fp32 kernel, used only if ws too small) ----------
#define FBM 32
#define FBK 64
#define FPK (FBK + 1)

__global__ __launch_bounds__(256) void moe_gate_fused(const float* __restrict__ Ag,
                                                      const float* __restrict__ Bg,
                                                      float* __restrict__ out) {
    __shared__ float smem[FBM * FPK + EE * FPK];
    float* As = smem;
    float* Bs = smem + FBM * FPK;
    float* Scf = smem + FBM * FPK;

    const int t = threadIdx.x;
    const int bm0 = blockIdx.x * FBM;
    const int tm = t & 7;
    const int te = t >> 3;
    float acc[4][5];
    #pragma unroll
    for (int i = 0; i < 4; i++)
        #pragma unroll
        for (int j = 0; j < 5; j++) acc[i][j] = 0.f;
    const int lr = t >> 4;
    const int lc = (t & 15) << 2;
    const int aBase = (4 * tm) * FPK;
    const int bBase = (5 * te) * FPK;

    for (int k0 = 0; k0 < HH; k0 += FBK) {
        __syncthreads();
        {
            float4 v0 = *reinterpret_cast<const float4*>(Ag + (size_t)(bm0 + lr) * HH + k0 + lc);
            float4 v1 = *reinterpret_cast<const float4*>(Ag + (size_t)(bm0 + lr + 16) * HH + k0 + lc);
            As[lr * FPK + lc + 0] = v0.x; As[lr * FPK + lc + 1] = v0.y;
            As[lr * FPK + lc + 2] = v0.z; As[lr * FPK + lc + 3] = v0.w;
            As[(lr + 16) * FPK + lc + 0] = v1.x; As[(lr + 16) * FPK + lc + 1] = v1.y;
            As[(lr + 16) * FPK + lc + 2] = v1.z; As[(lr + 16) * FPK + lc + 3] = v1.w;
        }
        #pragma unroll
        for (int i = 0; i < 10; i++) {
            int e = lr + 16 * i;
            float4 v = *reinterpret_cast<const float4*>(Bg + (size_t)e * HH + k0 + lc);
            Bs[e * FPK + lc + 0] = v.x; Bs[e * FPK + lc + 1] = v.y;
            Bs[e * FPK + lc + 2] = v.z; Bs[e * FPK + lc + 3] = v.w;
        }
        __syncthreads();
        #pragma unroll 4
        for (int k = 0; k < FBK; k++) {
            float a0 = As[aBase + 0 * FPK + k], a1 = As[aBase + 1 * FPK + k];
            float a2 = As[aBase + 2 * FPK + k], a3 = As[aBase + 3 * FPK + k];
            float b0 = Bs[bBase + 0 * FPK + k], b1 = Bs[bBase + 1 * FPK + k];
            float b2 = Bs[bBase + 2 * FPK + k], b3 = Bs[bBase + 3 * FPK + k];
            float b4 = Bs[bBase + 4 * FPK + k];
            acc[0][0] = fmaf(a0, b0, acc[0][0]); acc[0][1] = fmaf(a0, b1, acc[0][1]);
            acc[0][2] = fmaf(a0, b2, acc[0][2]); acc[0][3] = fmaf(a0, b3, acc[0][3]);
            acc[0][4] = fmaf(a0, b4, acc[0][4]);
            acc[1][0] = fmaf(a1, b0, acc[1][0]); acc[1][1] = fmaf(a1, b1, acc[1][1]);
            acc[1][2] = fmaf(a1, b2, acc[1][2]); acc[1][3] = fmaf(a1, b3, acc[1][3]);
            acc[1][4] = fmaf(a1, b4, acc[1][4]);
            acc[2][0] = fmaf(a2, b0, acc[2][0]); acc[2][1] = fmaf(a2, b1, acc[2][1]);
            acc[2][2] = fmaf(a2, b2, acc[2][2]); acc[2][3] = fmaf(a2, b3, acc[2][3]);
            acc[2][4] = fmaf(a2, b4, acc[2][4]);
            acc[3][0] = fmaf(a3, b0, acc[3][0]); acc[3][1] = fmaf(a3, b1, acc[3][1]);
            acc[3][2] = fmaf(a3, b2, acc[3][2]); acc[3][3] = fmaf(a3, b3, acc[3][3]);
            acc[3][4] = fmaf(a3, b4, acc[3][4]);
        }
    }
    __syncthreads();
    #pragma unroll
    for (int i = 0; i < 4; i++)
        #pragma unroll
        for (int j = 0; j < 5; j++)
            Scf[(4 * tm + i) * PS + (5 * te + j)] = acc[i][j];
    __syncthreads();

    const int w = t >> 6;
    const int l = t & 63;
    for (int it = 0; it < 8; ++it) {
        const int r = w * 8 + it;
        float s0 = Scf[r * PS + l];
        float s1 = Scf[r * PS + 64 + l];
        float s2 = (l < 32) ? Scf[r * PS + 128 + l] : -INFINITY;
        float m = fmaxf(s0, fmaxf(s1, s2));
        #pragma unroll
        for (int off = 32; off >= 1; off >>= 1) m = fmaxf(m, __shfl_xor(m, off, 64));
        float p0 = expf(s0 - m), p1 = expf(s1 - m);
        float p2 = (l < 32) ? expf(s2 - m) : 0.f;
        float sum = p0 + p1 + p2;
        #pragma unroll
        for (int off = 32; off >= 1; off >>= 1) sum += __shfl_xor(sum, off, 64);
        float inv = 1.0f / sum;
        p0 *= inv; p1 *= inv; p2 *= inv;
        const int g0 = l / GSZ, g1 = (l + 64) / GSZ, g2 = (l + 128) / GSZ;
        float gmax[NGRP];
        #pragma unroll
        for (int g = 0; g < NGRP; g++) {
            float v = -1.f;
            if (g0 == g) v = p0;
            if (g1 == g) v = fmaxf(v, p1);
            if (l < 32 && g2 == g) v = fmaxf(v, p2);
            #pragma unroll
            for (int off = 32; off >= 1; off >>= 1) v = fmaxf(v, __shfl_xor(v, off, 64));
            gmax[g] = v;
        }
        int selmask = 0;
        #pragma unroll
        for (int s = 0; s < TOPKG; s++) {
            float best = -2.f; int bg = 0;
            #pragma unroll
            for (int g = 0; g < NGRP; g++)
                if (!((selmask >> g) & 1) && gmax[g] > best) { best = gmax[g]; bg = g; }
            selmask |= 1 << bg;
        }
        float m0 = ((selmask >> g0) & 1) ? p0 : 0.f;
        float m1 = ((selmask >> g1) & 1) ? p1 : 0.f;
        float m2 = (l < 32) ? (((selmask >> g2) & 1) ? p2 : 0.f) : -1.f;
        #pragma unroll
        for (int s = 0; s < TOPK; s++) {
            float v = fmaxf(m0, fmaxf(m1, m2));
            #pragma unroll
            for (int off = 32; off >= 1; off >>= 1) v = fmaxf(v, __shfl_xor(v, off, 64));
            int idx = 0x7fffffff;
            if (m0 == v) idx = l;
            if (m1 == v) idx = min(idx, l + 64);
            if (l < 32 && m2 == v) idx = min(idx, l + 128);
            #pragma unroll
            for (int off = 32; off >= 1; off >>= 1) idx = min(idx, __shfl_xor(idx, off, 64));
            if (idx == l)            m0 = -1.f;
            else if (idx == l + 64)  m1 = -1.f;
            else if (l < 32 && idx == l + 128) m2 = -1.f;
            if (l == 0) out[(size_t)(bm0 + r) * TOPK + s] = v * RSCALE;
        }
    }
}

extern "C" void kernel_launch(void* const* d_in, const int* in_sizes, int n_in,
                              void* d_out, int out_size, void* d_ws, size_t ws_size,
                              hipStream_t stream) {
    const float* hs = (const float*)d_in[0];   // [8192][5120] fp32
    const float* kn = (const float*)d_in[1];   // [160][5120] fp32
    float* o = (float*)d_out;                  // [8192][6] fp32

    const size_t bwBytes = 2 * BW_ELEMS * sizeof(ushort);  // 3,276,800 (hi + lo)
    if (ws_size >= bwBytes) {
        ushort* Bw = (ushort*)d_ws;
        hipLaunchKernelGGL(prep_b, dim3(400), dim3(256), 0, stream, kn, Bw);
        hipLaunchKernelGGL(moe_mfma, dim3(TT / BM), dim3(512), 0, stream, hs, Bw, o);
    } else {
        hipLaunchKernelGGL(moe_gate_fused, dim3(TT / FBM), dim3(256), 0, stream, hs, kn, o);
    }
}